// Round 3
// baseline (12942.914 us; speedup 1.0000x reference)
//
#include <hip/hip_runtime.h>
#include <cstddef>
#include <cstdint>

#define T_TOTAL 32768
#define IN_SZ   128
#define HID     256
#define G4      1024
#define TA      48
#define TD      12
#define NDEC    4
#define N_WINS  (T_TOTAL - IN_SZ + 1)   // 32641
#define N_OUT   (N_WINS - TA)           // 32593

// ---------------- workspace layout (float offsets) ----------------
#define LEVS_OFF   ((size_t)0)                                   // 32768
#define PBF_OFF(l) ((size_t)32768 + (size_t)(l)*131072)          // bf16 frag-packed Whh, 4 x 131072 floats (512KB)
#define PIH0_OFF   ((size_t)557056)                              // 131072
#define PIH_OFF(l) ((size_t)688128 + (size_t)((l)-1)*262144)     // l=1..3
#define BS_OFF(l)  ((size_t)1474560 + (size_t)(l)*1024)          // 4 x 1024
#define NLWT_OFF   ((size_t)1478656)                             // 65536
#define H0_OFF     ((size_t)1544192)                             // 8343808
#define H1_OFF     ((size_t)(1544192 + 8343808))
#define H2_OFF     ((size_t)(1544192 + 2*8343808))
#define XP_OFF     ((size_t)(1544192 + (size_t)3*8343808))       // 33375232
#define WS_FLOATS  ((size_t)(XP_OFF + 33375232))                 // 59950848 (~240 MB)

typedef short s16x8 __attribute__((ext_vector_type(8)));
typedef float f32x16 __attribute__((ext_vector_type(16)));
typedef unsigned short ushort_t;
typedef unsigned int uint_t;

__device__ __forceinline__ float sig_fast(float x) {
  return __builtin_amdgcn_rcpf(1.f + __expf(-x));
}
__device__ __forceinline__ float tanh_fast(float x) {
  float ax = fabsf(x);
  float e  = __expf(-2.f * ax);
  float r  = (1.f - e) * __builtin_amdgcn_rcpf(1.f + e);
  return copysignf(r, x);
}
__device__ __forceinline__ ushort_t f2bf(float f) {
  uint_t u = __builtin_bit_cast(uint_t, f);
  uint_t r = (u + 0x7fffu + ((u >> 16) & 1u)) >> 16;
  return (ushort_t)r;
}

// ---------------- levels: contraction => 64-step lookback, fully parallel ----
__global__ void levels_kernel(const float* __restrict__ train,
                              const int* __restrict__ idxs,
                              const float* __restrict__ a0,
                              const float* __restrict__ tau_p,
                              float* __restrict__ levs) {
  int t = blockIdx.x * blockDim.x + threadIdx.x;
  if (t >= T_TOTAL) return;
  int ix   = idxs[0];
  float a  = 1.f / (1.f + __expf(-a0[ix]));
  float fl = tau_p[ix] * 1.0f;
  int q0 = (t >= 64) ? (t - 64) : 0;
  float p = fmaxf(train[q0], fl);
  for (int s = q0 + 1; s <= t; ++s)
    p = fmaxf(a * train[s] + (1.f - a) * p, fl);
  levs[t] = p;
}

// ---------------- act output (exact) ----------------
__global__ void act_kernel(const float* __restrict__ train,
                           const float* __restrict__ levs,
                           float* __restrict__ outp) {
  int idx = blockIdx.x * blockDim.x + threadIdx.x;
  if (idx >= N_OUT * NDEC) return;
  int w = idx >> 2, dec = idx & 3;
  int base = w + IN_SZ + dec * TD;
  float m = train[base];
#pragma unroll
  for (int j = 1; j < TD; ++j) m = fmaxf(m, train[base + j]);
  outp[idx] = m / levs[w + IN_SZ - 1];
}

// ---------------- packing ----------------
// Column mapping (all gate buffers): N = (c>>6)*256 + g*64 + (c&63)
// i.e. wave w=N>>8 owns cells [w*64, w*64+64), local col = g*64 + c'
__global__ void pack_w_kernel(const float* __restrict__ W, float* __restrict__ P, int K) {
  int idx = blockIdx.x * blockDim.x + threadIdx.x;
  if (idx >= K * G4) return;
  int kk = idx >> 10, N = idx & 1023;
  int g = (N >> 6) & 3;
  int c = ((N >> 8) << 6) + (N & 63);
  P[idx] = W[(size_t)(g * HID + c) * K + kk];
}
__global__ void pack_b_kernel(const float* __restrict__ bih, const float* __restrict__ bhh,
                              float* __restrict__ bs) {
  int idx = blockIdx.x * blockDim.x + threadIdx.x;
  if (idx >= G4) return;
  int g = (idx >> 6) & 3;
  int c = ((idx >> 8) << 6) + (idx & 63);
  bs[idx] = bih[g * HID + c] + bhh[g * HID + c];
}
// Whh -> bf16 B-fragment stream for mfma_f32_32x32x16_bf16.
// Frag order: [w(4)][s16(16)][t(8)] ; within frag: [lane(64)][j(8)]
// B[k][n]: k = s16*16 + (l>>5)*8 + j ; tile col n = t*32 + (l&31)
// local col n = g*64 + c'  (g = t>>1, c' = (t&1)*32 + (l&31))
__global__ void pack_pb_kernel(const float* __restrict__ Whh, ushort_t* __restrict__ PB) {
  int idx = blockIdx.x * blockDim.x + threadIdx.x;
  if (idx >= 262144) return;
  int j = idx & 7;
  int l = (idx >> 3) & 63;
  int frag = idx >> 9;
  int t = frag & 7;
  int s16 = (frag >> 3) & 15;
  int w = frag >> 7;
  int k = s16 * 16 + ((l >> 5) << 3) + j;
  int g = t >> 1;
  int cp = ((t & 1) << 5) + (l & 31);
  int orow = g * HID + w * 64 + cp;
  PB[idx] = f2bf(Whh[(size_t)orow * HID + k]);
}
__global__ void pack_nlwt_kernel(const float* __restrict__ nlW, float* __restrict__ nlWT) {
  int idx = blockIdx.x * blockDim.x + threadIdx.x;
  if (idx >= HID * HID) return;
  int k = idx >> 8, j = idx & 255;
  nlWT[idx] = nlW[j * HID + k];
}

// ---------------- generic tiled GEMM: C = act(A(+A2) @ B + bias) ------------
__global__ __launch_bounds__(256, 2) void gemm_kernel(
    const float* __restrict__ A, const float* __restrict__ A2,
    const float* __restrict__ B, const float* __restrict__ bias,
    float* __restrict__ C, int M, int N, int K, int act_tanh) {
  __shared__ float As[32][64];
  __shared__ float Bs[32][64];
  int m0 = blockIdx.x * 64, n0 = blockIdx.y * 64;
  int tid = threadIdx.x;
  int tr = tid >> 4, tc = tid & 15;
  float acc[4][4] = {};
  for (int k0 = 0; k0 < K; k0 += 32) {
    {
      int lm = tid >> 3;
      int lk = (tid & 7) * 4;
#pragma unroll
      for (int half = 0; half < 2; ++half) {
        int m = m0 + lm + half * 32;
        float4 v = make_float4(0.f, 0.f, 0.f, 0.f);
        if (m < M) {
          v = *(const float4*)(A + (size_t)m * K + k0 + lk);
          if (A2) {
            float4 w = *(const float4*)(A2 + (size_t)m * K + k0 + lk);
            v.x += w.x; v.y += w.y; v.z += w.z; v.w += w.w;
          }
        }
        As[lk + 0][lm + half * 32] = v.x;
        As[lk + 1][lm + half * 32] = v.y;
        As[lk + 2][lm + half * 32] = v.z;
        As[lk + 3][lm + half * 32] = v.w;
      }
    }
    {
      int lk = tid >> 3;
      int ln = (tid & 7) * 8;
      const float* src = B + (size_t)(k0 + lk) * N + n0 + ln;
      *(float4*)&Bs[lk][ln]     = *(const float4*)src;
      *(float4*)&Bs[lk][ln + 4] = *(const float4*)(src + 4);
    }
    __syncthreads();
#pragma unroll
    for (int k = 0; k < 32; ++k) {
      const float4 av4 = *(const float4*)&As[k][tr * 4];
      const float4 bv4 = *(const float4*)&Bs[k][tc * 4];
      const float a_[4] = {av4.x, av4.y, av4.z, av4.w};
      const float b_[4] = {bv4.x, bv4.y, bv4.z, bv4.w};
#pragma unroll
      for (int i2 = 0; i2 < 4; ++i2)
#pragma unroll
        for (int j2 = 0; j2 < 4; ++j2)
          acc[i2][j2] = fmaf(a_[i2], b_[j2], acc[i2][j2]);
    }
    __syncthreads();
  }
  const float4 bias4 = *(const float4*)&bias[n0 + tc * 4];
  const float bb[4] = {bias4.x, bias4.y, bias4.z, bias4.w};
#pragma unroll
  for (int i2 = 0; i2 < 4; ++i2) {
    int m = m0 + tr * 4 + i2;
    if (m < M) {
      float4 o;
      o.x = acc[i2][0] + bb[0];
      o.y = acc[i2][1] + bb[1];
      o.z = acc[i2][2] + bb[2];
      o.w = acc[i2][3] + bb[3];
      if (act_tanh) {
        o.x = tanh_fast(o.x); o.y = tanh_fast(o.y);
        o.z = tanh_fast(o.z); o.w = tanh_fast(o.w);
      }
      *(float4*)(C + (size_t)m * N + n0 + tc * 4) = o;
    }
  }
}

// ---------------- layer-0 input projection from sliding windows -------------
__global__ __launch_bounds__(256, 2) void gemm_win_kernel(
    const float* __restrict__ train, const float* __restrict__ levs,
    const float* __restrict__ B, const float* __restrict__ bias,
    float* __restrict__ C) {
  __shared__ float trs[192];
  __shared__ float ils[64];
  __shared__ float Bs[32][64];
  int m0 = blockIdx.x * 64, n0 = blockIdx.y * 64;
  int tid = threadIdx.x;
  int tr = tid >> 4, tc = tid & 15;
  if (tid < 192) {
    int tt = m0 + tid;
    trs[tid] = (tt < T_TOTAL) ? train[tt] : 0.f;
  }
  if (tid < 64) {
    int m = m0 + tid;
    ils[tid] = (m < N_OUT) ? (1.f / levs[m + IN_SZ - 1]) : 0.f;
  }
  float acc[4][4] = {};
  for (int k0 = 0; k0 < IN_SZ; k0 += 32) {
    int lk = tid >> 3, ln = (tid & 7) * 8;
    const float* src = B + (size_t)(k0 + lk) * G4 + n0 + ln;
    *(float4*)&Bs[lk][ln]     = *(const float4*)src;
    *(float4*)&Bs[lk][ln + 4] = *(const float4*)(src + 4);
    __syncthreads();
#pragma unroll
    for (int k = 0; k < 32; ++k) {
      const float4 bv4 = *(const float4*)&Bs[k][tc * 4];
      const float b_[4] = {bv4.x, bv4.y, bv4.z, bv4.w};
#pragma unroll
      for (int i2 = 0; i2 < 4; ++i2) {
        float a = trs[tr * 4 + i2 + k0 + k];
#pragma unroll
        for (int j2 = 0; j2 < 4; ++j2)
          acc[i2][j2] = fmaf(a, b_[j2], acc[i2][j2]);
      }
    }
    __syncthreads();
  }
  const float4 bias4 = *(const float4*)&bias[n0 + tc * 4];
  const float bb[4] = {bias4.x, bias4.y, bias4.z, bias4.w};
#pragma unroll
  for (int i2 = 0; i2 < 4; ++i2) {
    int m = m0 + tr * 4 + i2;
    if (m < N_OUT) {
      float s = ils[tr * 4 + i2];
      float4 o;
      o.x = acc[i2][0] * s + bb[0];
      o.y = acc[i2][1] * s + bb[1];
      o.z = acc[i2][2] * s + bb[2];
      o.w = acc[i2][3] * s + bb[3];
      *(float4*)(C + (size_t)m * G4 + n0 + tc * 4) = o;
    }
  }
}

// ---------------- MFMA segment-parallel LSTM ----------------
// M=32 chains/WG, 4 waves; wave w owns gate-cols for cells [w*64, w*64+64).
// Per wave-step: 16 K-steps x 8 N-tiles of mfma_f32_32x32x16_bf16.
// Gates fully lane-local (col packing n = g*64 + c'); cst fp32 in regs.
__global__ __launch_bounds__(256, 1) void lstm_mfma_kernel(
    const float* __restrict__ XP,     // [N_OUT][1024] fp32, packed cols, bias baked
    const ushort_t* __restrict__ PBu, // bf16 B-frag stream
    float* __restrict__ hout,         // [N_OUT][256]
    int d, int Sper, int P, int W, int L) {
  __shared__ ushort_t Abuf[32][264];  // h as bf16, row = chain, col = cell (pad 264)
  const int tid = threadIdx.x;
  const int w  = tid >> 6;
  const int l  = tid & 63;
  const int hi = l >> 5;
  const int lm = l & 31;

  for (int idx = tid; idx < 32 * 264; idx += 256) ((ushort_t*)Abuf)[idx] = 0;

  int p0v[16], dlv[16];
#pragma unroll
  for (int rr = 0; rr < 16; ++rr) {
    int r  = (rr & 3) + ((rr >> 2) << 3) + (hi << 2);
    int id = blockIdx.x * 32 + r;
    int dl = id / Sper;
    int s  = id - dl * Sper;
    if (dl >= d) { p0v[rr] = L + W; dlv[rr] = 0; }
    else         { p0v[rr] = s * P; dlv[rr] = dl; }
  }
  float cst[32];
#pragma unroll
  for (int z = 0; z < 32; ++z) cst[z] = 0.f;

  f32x16 vzero;
#pragma unroll
  for (int e = 0; e < 16; ++e) vzero[e] = 0.f;

  const s16x8* pbw = (const s16x8*)(PBu + (size_t)w * (16 * 8 * 512));
  const ushort_t* abase = &Abuf[0][0];

  __syncthreads();

  const int steps = W + P;
  for (int i = 0; i < steps; ++i) {
    // ---- MFMA phase: preact[32 rows][256 cols-per-wave] ----
    f32x16 acc[8];
#pragma unroll
    for (int t = 0; t < 8; ++t) acc[t] = vzero;

#pragma unroll
    for (int s16 = 0; s16 < 16; ++s16) {
      s16x8 af = *(const s16x8*)(abase + (size_t)lm * 264 + (s16 * 16 + hi * 8));
#pragma unroll
      for (int t = 0; t < 8; ++t) {
        s16x8 bf = pbw[(size_t)(s16 * 8 + t) * 64 + l];
        acc[t] = __builtin_amdgcn_mfma_f32_32x32x16_bf16(af, bf, acc[t], 0, 0, 0);
      }
    }
    __syncthreads();   // A-frag reads done before Abuf rewrite

    // ---- gate phase: lane-local i,f,g,o for (16 rows x 2 cells) ----
#pragma unroll
    for (int rr = 0; rr < 16; ++rr) {
      int r  = (rr & 3) + ((rr >> 2) << 3) + (hi << 2);
      int p0 = p0v[rr];
      int q0 = p0 - W; if (q0 < 0) q0 = 0;
      int q  = q0 + i;
      int p1 = p0 + P; if (p1 > L) p1 = L;
      int t  = q * d + dlv[rr];
      bool valid = (q < p1) && (t < N_OUT);
#pragma unroll
      for (int ch = 0; ch < 2; ++ch) {
        float xi0 = 0.f, xi1 = 0.f, xi2 = 0.f, xi3 = 0.f;
        if (valid) {
          const float* xr = XP + (size_t)t * G4 + w * 256 + ch * 32 + lm;
          xi0 = xr[0]; xi1 = xr[64]; xi2 = xr[128]; xi3 = xr[192];
        }
        float pi = acc[0 + ch][rr] + xi0;
        float pf = acc[2 + ch][rr] + xi1;
        float pg = acc[4 + ch][rr] + xi2;
        float po = acc[6 + ch][rr] + xi3;
        float hh = 0.f;
        if (valid) {
          float cs = sig_fast(pf) * cst[rr * 2 + ch] + sig_fast(pi) * tanh_fast(pg);
          cst[rr * 2 + ch] = cs;
          hh = sig_fast(po) * tanh_fast(cs);
          if (q >= p0)
            hout[(size_t)t * HID + w * 64 + ch * 32 + lm] = hh;
        }
        Abuf[r][w * 64 + ch * 32 + lm] = f2bf(hh);
      }
    }
    __syncthreads();
  }
}

// ---------------- final 4-way head ----------------
__global__ void pred_kernel(const float* __restrict__ outb,
                            const float* __restrict__ scW,
                            const float* __restrict__ scb,
                            float* __restrict__ pred) {
  int idx = blockIdx.x * blockDim.x + threadIdx.x;
  if (idx >= N_OUT * NDEC) return;
  int t = idx >> 2, e = idx & 3;
  const float* orow = outb + (size_t)t * HID;
  const float* wrow = scW + e * HID;
  float s = 0.f;
#pragma unroll 4
  for (int k = 0; k < HID; k += 4) {
    float4 ov = *(const float4*)(orow + k);
    float4 wv = *(const float4*)(wrow + k);
    s = fmaf(ov.x, wv.x, s);
    s = fmaf(ov.y, wv.y, s);
    s = fmaf(ov.z, wv.z, s);
    s = fmaf(ov.w, wv.w, s);
  }
  pred[idx] = s + scb[e];
}

extern "C" void kernel_launch(void* const* d_in, const int* in_sizes, int n_in,
                              void* d_out, int out_size, void* d_ws, size_t ws_size,
                              hipStream_t stream) {
  if (ws_size < WS_FLOATS * sizeof(float)) return;

  const float* train = (const float*)d_in[0];
  const int*   idxs  = (const int*)d_in[1];
  const float* a0    = (const float*)d_in[2];
  const float* tau_p = (const float*)d_in[3];
  const float* Wih[4] = {(const float*)d_in[4], (const float*)d_in[8],
                         (const float*)d_in[12], (const float*)d_in[16]};
  const float* Whh[4] = {(const float*)d_in[5], (const float*)d_in[9],
                         (const float*)d_in[13], (const float*)d_in[17]};
  const float* bih[4] = {(const float*)d_in[6], (const float*)d_in[10],
                         (const float*)d_in[14], (const float*)d_in[18]};
  const float* bhh[4] = {(const float*)d_in[7], (const float*)d_in[11],
                         (const float*)d_in[15], (const float*)d_in[19]};
  const float* nlW = (const float*)d_in[20];
  const float* nlb = (const float*)d_in[21];
  const float* scW = (const float*)d_in[22];
  const float* scb = (const float*)d_in[23];

  float* ws   = (float*)d_ws;
  float* levs = ws + LEVS_OFF;
  ushort_t* PB[4];
  float* Pih[4]; float* Bsum[4];
  for (int lidx = 0; lidx < 4; ++lidx) {
    PB[lidx]   = (ushort_t*)(ws + PBF_OFF(lidx));
    Bsum[lidx] = ws + BS_OFF(lidx);
  }
  Pih[0] = ws + PIH0_OFF;
  for (int lidx = 1; lidx < 4; ++lidx) Pih[lidx] = ws + PIH_OFF(lidx);
  float* nlWT = ws + NLWT_OFF;
  float* H0 = ws + H0_OFF;
  float* H1 = ws + H1_OFF;
  float* H2 = ws + H2_OFF;
  float* H3 = H0;                 // layer-3 output aliases H0 (dead by then)
  float* XP = ws + XP_OFF;

  // ---- packing ----
  for (int lidx = 0; lidx < 4; ++lidx)
    hipLaunchKernelGGL(pack_pb_kernel, dim3(1024), dim3(256), 0, stream, Whh[lidx], PB[lidx]);
  hipLaunchKernelGGL(pack_w_kernel, dim3(512), dim3(256), 0, stream, Wih[0], Pih[0], IN_SZ);
  for (int lidx = 1; lidx < 4; ++lidx)
    hipLaunchKernelGGL(pack_w_kernel, dim3(1024), dim3(256), 0, stream, Wih[lidx], Pih[lidx], HID);
  for (int lidx = 0; lidx < 4; ++lidx)
    hipLaunchKernelGGL(pack_b_kernel, dim3(4), dim3(256), 0, stream, bih[lidx], bhh[lidx], Bsum[lidx]);
  hipLaunchKernelGGL(pack_nlwt_kernel, dim3(256), dim3(256), 0, stream, nlW, nlWT);

  // ---- levels + act ----
  hipLaunchKernelGGL(levels_kernel, dim3(128), dim3(256), 0, stream, train, idxs, a0, tau_p, levs);
  hipLaunchKernelGGL(act_kernel, dim3(510), dim3(256), 0, stream, train, levs,
                     (float*)d_out + (size_t)N_OUT * NDEC);

  // ---- layer 0: d=1, 4096 segs x P=8, W=64 -> 128 WGs x 72 steps ----
  hipLaunchKernelGGL(gemm_win_kernel, dim3(510, 16), dim3(256), 0, stream,
                     train, levs, Pih[0], Bsum[0], XP);
  hipLaunchKernelGGL(lstm_mfma_kernel, dim3(128), dim3(256), 0, stream,
                     XP, PB[0], H0, 1, 4096, 8, 64, 32593);
  // ---- layer 1: d=3, 3 x 1360 segs -> 128 WGs ----
  hipLaunchKernelGGL(gemm_kernel, dim3(510, 16), dim3(256), 0, stream,
                     H0, (const float*)nullptr, Pih[1], Bsum[1], XP, N_OUT, G4, HID, 0);
  hipLaunchKernelGGL(lstm_mfma_kernel, dim3(128), dim3(256), 0, stream,
                     XP, PB[1], H1, 3, 1360, 8, 64, 10865);
  // ---- layer 2: d=6, 6 x 680 segs -> 128 WGs ----
  hipLaunchKernelGGL(gemm_kernel, dim3(510, 16), dim3(256), 0, stream,
                     H1, (const float*)nullptr, Pih[2], Bsum[2], XP, N_OUT, G4, HID, 0);
  hipLaunchKernelGGL(lstm_mfma_kernel, dim3(128), dim3(256), 0, stream,
                     XP, PB[2], H2, 6, 680, 8, 64, 5433);
  // ---- layer 3: d=12, 12 x 340 segs -> 128 WGs ----
  hipLaunchKernelGGL(gemm_kernel, dim3(510, 16), dim3(256), 0, stream,
                     H2, (const float*)nullptr, Pih[3], Bsum[3], XP, N_OUT, G4, HID, 0);
  hipLaunchKernelGGL(lstm_mfma_kernel, dim3(128), dim3(256), 0, stream,
                     XP, PB[3], H3, 12, 340, 8, 64, 2717);

  // ---- epilogue: out = tanh((H1+H3) @ nlW^T + nlb); pred = out @ scW^T + scb ----
  hipLaunchKernelGGL(gemm_kernel, dim3(510, 4), dim3(256), 0, stream,
                     H1, H3, nlWT, nlb, XP, N_OUT, HID, HID, 1);
  hipLaunchKernelGGL(pred_kernel, dim3(510), dim3(256), 0, stream,
                     XP, scW, scb, (float*)d_out);
}

// Round 4
// 9725.648 us; speedup vs baseline: 1.3308x; 1.3308x over previous
//
#include <hip/hip_runtime.h>
#include <cstddef>
#include <cstdint>

#define T_TOTAL 32768
#define IN_SZ   128
#define HID     256
#define G4      1024
#define TA      48
#define TD      12
#define NDEC    4
#define N_WINS  (T_TOTAL - IN_SZ + 1)   // 32641
#define N_OUT   (N_WINS - TA)           // 32593
#define MPAD    32640                   // padded row count (255*128)
#define W48     48
#define P4      4
#define NSTEPS  (W48 + P4)              // 52

// ---------------- workspace layout (float offsets) ----------------
#define LEVS_OFF   ((size_t)0)                                    // 32768
#define PBW_OFF(l) ((size_t)32768 + (size_t)(l)*131072)           // Whh bf16 frags, 4 x 131072
#define PBI0_OFF   ((size_t)557056)                               // Wih0 frags, 65536
#define PBI_OFF(l) ((size_t)622592 + (size_t)((l)-1)*131072)      // Wih1..3 frags
#define PBNL_OFF   ((size_t)1015808)                              // nlW frags, 32768
#define BS_OFF(l)  ((size_t)1048576 + (size_t)(l)*1024)           // 4 x 1024
#define XPB_OFF    ((size_t)1052672)                              // XP bf16 [32640][1024] = 16711680 fl
#define HB_OFF(l)  ((size_t)17764352 + (size_t)(l)*4177920)       // h bf16 [32640][256], 4 x
#define OUTF_OFF   ((size_t)34476032)                             // fp32 [32640][256] = 8355840
#define WS_FLOATS  ((size_t)(34476032 + 8355840))                 // 42831872 (~171 MB)

typedef short s16x8 __attribute__((ext_vector_type(8)));
typedef float f32x16 __attribute__((ext_vector_type(16)));
typedef unsigned short ushort_t;
typedef unsigned int uint_t;

__device__ __forceinline__ float sig_fast(float x) {
  return __builtin_amdgcn_rcpf(1.f + __expf(-x));
}
__device__ __forceinline__ float tanh_fast(float x) {
  float ax = fabsf(x);
  float e  = __expf(-2.f * ax);
  float r  = (1.f - e) * __builtin_amdgcn_rcpf(1.f + e);
  return copysignf(r, x);
}
__device__ __forceinline__ ushort_t f2bf(float f) {
  uint_t u = __builtin_bit_cast(uint_t, f);
  uint_t r = (u + 0x7fffu + ((u >> 16) & 1u)) >> 16;
  return (ushort_t)r;
}
__device__ __forceinline__ float bf2f(uint_t us) {
  return __builtin_bit_cast(float, us << 16);
}

// ---------------- levels (contraction, 64-step lookback) ----------------
__global__ void levels_kernel(const float* __restrict__ train,
                              const int* __restrict__ idxs,
                              const float* __restrict__ a0,
                              const float* __restrict__ tau_p,
                              float* __restrict__ levs) {
  int t = blockIdx.x * blockDim.x + threadIdx.x;
  if (t >= T_TOTAL) return;
  int ix   = idxs[0];
  float a  = 1.f / (1.f + __expf(-a0[ix]));
  float fl = tau_p[ix] * 1.0f;
  int q0 = (t >= 64) ? (t - 64) : 0;
  float p = fmaxf(train[q0], fl);
  for (int s = q0 + 1; s <= t; ++s)
    p = fmaxf(a * train[s] + (1.f - a) * p, fl);
  levs[t] = p;
}

// ---------------- act output (exact) ----------------
__global__ void act_kernel(const float* __restrict__ train,
                           const float* __restrict__ levs,
                           float* __restrict__ outp) {
  int idx = blockIdx.x * blockDim.x + threadIdx.x;
  if (idx >= N_OUT * NDEC) return;
  int w = idx >> 2, dec = idx & 3;
  int base = w + IN_SZ + dec * TD;
  float m = train[base];
#pragma unroll
  for (int j = 1; j < TD; ++j) m = fmaxf(m, train[base + j]);
  outp[idx] = m / levs[w + IN_SZ - 1];
}

// ---------------- packing ----------------
// B-frag stream for mfma_f32_32x32x16_bf16 over cols in gate-major packed order:
// global packed col N = wv*256 + g*64 + cp ; frag = wv*(K16*8) + s16*8 + t
// element [l][j]: k = s16*16 + (l>>5)*8 + j ; col-in-block = t*32+(l&31) -> g=t>>1, cp=(t&1)*32+(l&31)
__global__ void pack_pb_kernel(const float* __restrict__ Wsrc, ushort_t* __restrict__ PB, int K16) {
  int idx = blockIdx.x * blockDim.x + threadIdx.x;
  if (idx >= K16 * 16384) return;
  int j = idx & 7;
  int l = (idx >> 3) & 63;
  int frag = idx >> 9;
  int t = frag & 7;
  int s16 = (frag >> 3) % K16;
  int wv  = (frag >> 3) / K16;
  int K = K16 * 16;
  int k = s16 * 16 + ((l >> 5) << 3) + j;
  int g = t >> 1;
  int cp = ((t & 1) << 5) + (l & 31);
  int orow = g * HID + wv * 64 + cp;
  PB[idx] = f2bf(Wsrc[(size_t)orow * K + k]);
}
// nlW frags: natural cols, N=256 as 2 blocks of 128 (4 tiles each)
__global__ void pack_nl_kernel(const float* __restrict__ nlW, ushort_t* __restrict__ PBnl) {
  int idx = blockIdx.x * blockDim.x + threadIdx.x;
  if (idx >= 65536) return;
  int j = idx & 7;
  int l = (idx >> 3) & 63;
  int frag = idx >> 9;
  int t = frag & 3;
  int s16 = (frag >> 2) & 15;
  int nb = frag >> 6;
  int n = nb * 128 + t * 32 + (l & 31);
  int k = s16 * 16 + ((l >> 5) << 3) + j;
  PBnl[idx] = f2bf(nlW[(size_t)n * HID + k]);
}
__global__ void pack_b_kernel(const float* __restrict__ bih, const float* __restrict__ bhh,
                              float* __restrict__ bs) {
  int idx = blockIdx.x * blockDim.x + threadIdx.x;
  if (idx >= G4) return;
  int g = (idx >> 6) & 3;
  int c = ((idx >> 8) << 6) + (idx & 63);
  bs[idx] = bih[g * HID + c] + bhh[g * HID + c];
}

// ---------------- MFMA input-projection GEMM (layers 1-3) ----------------
__global__ __launch_bounds__(256, 1) void gemm_xp_kernel(
    const ushort_t* __restrict__ Ab,   // [MPAD][256] bf16 (h of prev layer)
    const ushort_t* __restrict__ PBih, // frag stream (K16=16)
    const float* __restrict__ Bsum,    // [1024] gate-major packed
    ushort_t* __restrict__ XPb) {      // [MPAD][1024]
  int tid = threadIdx.x;
  int w = tid >> 6, l = tid & 63, hi = l >> 5, lm = l & 31;
  int mb = blockIdx.x, nb = blockIdx.y;
  int m = mb * 128 + w * 32 + lm;
  const s16x8* pbw = ((const s16x8*)PBih) + (size_t)nb * 8192;
  const s16x8* arow = (const s16x8*)(Ab + (size_t)m * 256);
  f32x16 acc[8];
#pragma unroll
  for (int t = 0; t < 8; ++t)
#pragma unroll
    for (int e = 0; e < 16; ++e) acc[t][e] = 0.f;
#pragma unroll
  for (int s16 = 0; s16 < 16; ++s16) {
    s16x8 af = arow[s16 * 2 + hi];
#pragma unroll
    for (int t = 0; t < 8; ++t) {
      s16x8 bf = pbw[(size_t)(s16 * 8 + t) * 64 + l];
      acc[t] = __builtin_amdgcn_mfma_f32_32x32x16_bf16(af, bf, acc[t], 0, 0, 0);
    }
  }
  float bsv[8];
#pragma unroll
  for (int t = 0; t < 8; ++t) bsv[t] = Bsum[nb * 256 + t * 32 + lm];
#pragma unroll
  for (int rr = 0; rr < 16; ++rr) {
    int r  = (rr & 3) + ((rr >> 2) << 3) + (hi << 2);
    int mo = mb * 128 + w * 32 + r;
    if (mo >= N_OUT) continue;
#pragma unroll
    for (int ch = 0; ch < 2; ++ch) {
      uint_t lo = (uint_t)f2bf(acc[0 + ch][rr] + bsv[0 + ch]) |
                  ((uint_t)f2bf(acc[2 + ch][rr] + bsv[2 + ch]) << 16);
      uint_t hi2 = (uint_t)f2bf(acc[4 + ch][rr] + bsv[4 + ch]) |
                   ((uint_t)f2bf(acc[6 + ch][rr] + bsv[6 + ch]) << 16);
      *(uint2*)(XPb + (size_t)mo * 1024 + nb * 256 + (ch * 32 + lm) * 4) = make_uint2(lo, hi2);
    }
  }
}

// ---------------- layer-0 window projection (A built from train/lev) -------
__global__ __launch_bounds__(256, 1) void gemm_win_kernel(
    const float* __restrict__ train, const float* __restrict__ levs,
    const ushort_t* __restrict__ PBih0, // frag stream (K16=8)
    const float* __restrict__ Bsum,
    ushort_t* __restrict__ XPb) {
  int tid = threadIdx.x;
  int w = tid >> 6, l = tid & 63, hi = l >> 5, lm = l & 31;
  int mb = blockIdx.x, nb = blockIdx.y;
  int m = mb * 128 + w * 32 + lm;                 // <= 32639; train reads <= 32766
  float s = 1.f / levs[m + IN_SZ - 1];
  const s16x8* pbw = ((const s16x8*)PBih0) + (size_t)nb * 4096;
  f32x16 acc[8];
#pragma unroll
  for (int t = 0; t < 8; ++t)
#pragma unroll
    for (int e = 0; e < 16; ++e) acc[t][e] = 0.f;
#pragma unroll
  for (int s16 = 0; s16 < 8; ++s16) {
    const float* tp = train + m + s16 * 16 + hi * 8;
    s16x8 af;
#pragma unroll
    for (int j = 0; j < 8; ++j) af[j] = (short)f2bf(tp[j] * s);
#pragma unroll
    for (int t = 0; t < 8; ++t) {
      s16x8 bf = pbw[(size_t)(s16 * 8 + t) * 64 + l];
      acc[t] = __builtin_amdgcn_mfma_f32_32x32x16_bf16(af, bf, acc[t], 0, 0, 0);
    }
  }
  float bsv[8];
#pragma unroll
  for (int t = 0; t < 8; ++t) bsv[t] = Bsum[nb * 256 + t * 32 + lm];
#pragma unroll
  for (int rr = 0; rr < 16; ++rr) {
    int r  = (rr & 3) + ((rr >> 2) << 3) + (hi << 2);
    int mo = mb * 128 + w * 32 + r;
    if (mo >= N_OUT) continue;
#pragma unroll
    for (int ch = 0; ch < 2; ++ch) {
      uint_t lo = (uint_t)f2bf(acc[0 + ch][rr] + bsv[0 + ch]) |
                  ((uint_t)f2bf(acc[2 + ch][rr] + bsv[2 + ch]) << 16);
      uint_t hi2 = (uint_t)f2bf(acc[4 + ch][rr] + bsv[4 + ch]) |
                   ((uint_t)f2bf(acc[6 + ch][rr] + bsv[6 + ch]) << 16);
      *(uint2*)(XPb + (size_t)mo * 1024 + nb * 256 + (ch * 32 + lm) * 4) = make_uint2(lo, hi2);
    }
  }
}

// ---------------- MFMA segment-parallel LSTM (v2) ----------------
__global__ __launch_bounds__(256, 1) void lstm_mfma_kernel(
    const ushort_t* __restrict__ XPb,  // [MPAD][1024] bf16 gate-packed
    const ushort_t* __restrict__ PBu,  // Whh frag stream
    ushort_t* __restrict__ Hb,         // [MPAD][256] bf16
    int d, int Sper, int L) {
  __shared__ ushort_t Abuf[32][264];
  const int tid = threadIdx.x;
  const int w  = tid >> 6;
  const int l  = tid & 63;
  const int hi = l >> 5;
  const int lm = l & 31;

  for (int idx = tid; idx < 32 * 264; idx += 256) ((ushort_t*)Abuf)[idx] = 0;

  int p0v[16], dlv[16];
#pragma unroll
  for (int rr = 0; rr < 16; ++rr) {
    int r  = (rr & 3) + ((rr >> 2) << 3) + (hi << 2);
    int id = blockIdx.x * 32 + r;
    int dl = id / Sper;
    int s  = id - dl * Sper;
    if (dl >= d) { p0v[rr] = L; dlv[rr] = 0; }   // sentinel; t-guard kills it
    else         { p0v[rr] = s * P4; dlv[rr] = dl; }
  }
  float cst[32];
#pragma unroll
  for (int z = 0; z < 32; ++z) cst[z] = 0.f;

  const s16x8* pbw = ((const s16x8*)PBu) + (size_t)w * 8192;
  __syncthreads();

  for (int i = 0; i < NSTEPS; ++i) {
    f32x16 acc[8];
#pragma unroll
    for (int t = 0; t < 8; ++t)
#pragma unroll
      for (int e = 0; e < 16; ++e) acc[t][e] = 0.f;

#pragma unroll
    for (int s16 = 0; s16 < 16; ++s16) {
      s16x8 af = *(const s16x8*)(&Abuf[lm][s16 * 16 + hi * 8]);
#pragma unroll
      for (int t = 0; t < 8; ++t) {
        s16x8 bf = pbw[(size_t)(s16 * 8 + t) * 64 + l];
        acc[t] = __builtin_amdgcn_mfma_f32_32x32x16_bf16(af, bf, acc[t], 0, 0, 0);
      }
    }
    __syncthreads();   // A-frag reads done before Abuf rewrite

#pragma unroll
    for (int rr = 0; rr < 16; ++rr) {
      int r  = (rr & 3) + ((rr >> 2) << 3) + (hi << 2);
      int p0 = p0v[rr];
      int q0 = p0 - W48; if (q0 < 0) q0 = 0;
      int q  = q0 + i;
      int p1 = p0 + P4; if (p1 > L) p1 = L;
      int t  = q * d + dlv[rr];
      bool valid = (q < p1) && (t < N_OUT);
#pragma unroll
      for (int ch = 0; ch < 2; ++ch) {
        uint2 xi = make_uint2(0u, 0u);
        if (valid)
          xi = *(const uint2*)(XPb + (size_t)t * 1024 + w * 256 + (ch * 32 + lm) * 4);
        float pi = acc[0 + ch][rr] + bf2f(xi.x & 0xffffu);
        float pf = acc[2 + ch][rr] + bf2f(xi.x >> 16);
        float pg = acc[4 + ch][rr] + bf2f(xi.y & 0xffffu);
        float po = acc[6 + ch][rr] + bf2f(xi.y >> 16);
        float hh = 0.f;
        if (valid) {
          float cs = sig_fast(pf) * cst[rr * 2 + ch] + sig_fast(pi) * tanh_fast(pg);
          cst[rr * 2 + ch] = cs;
          hh = sig_fast(po) * tanh_fast(cs);
          if (q >= p0)
            Hb[(size_t)t * HID + w * 64 + ch * 32 + lm] = f2bf(hh);
        }
        Abuf[r][w * 64 + ch * 32 + lm] = f2bf(hh);
      }
    }
    __syncthreads();
  }
}

// ---------------- epilogue: out = tanh((H1+H3) @ nlW^T + nlb), fp32 --------
__global__ __launch_bounds__(256, 2) void gemm_nl_kernel(
    const ushort_t* __restrict__ H1b, const ushort_t* __restrict__ H3b,
    const ushort_t* __restrict__ PBnl, const float* __restrict__ nlb,
    float* __restrict__ OutF) {
  int tid = threadIdx.x;
  int w = tid >> 6, l = tid & 63, hi = l >> 5, lm = l & 31;
  int mb = blockIdx.x, nb = blockIdx.y;
  int m = mb * 128 + w * 32 + lm;
  const s16x8* pbn = ((const s16x8*)PBnl) + (size_t)nb * 4096;
  const s16x8* a1 = (const s16x8*)(H1b + (size_t)m * 256);
  const s16x8* a3 = (const s16x8*)(H3b + (size_t)m * 256);
  f32x16 acc[4];
#pragma unroll
  for (int t = 0; t < 4; ++t)
#pragma unroll
    for (int e = 0; e < 16; ++e) acc[t][e] = 0.f;
#pragma unroll
  for (int s16 = 0; s16 < 16; ++s16) {
    s16x8 af1 = a1[s16 * 2 + hi];
    s16x8 af3 = a3[s16 * 2 + hi];
#pragma unroll
    for (int t = 0; t < 4; ++t) {
      s16x8 bf = pbn[(size_t)(s16 * 4 + t) * 64 + l];
      acc[t] = __builtin_amdgcn_mfma_f32_32x32x16_bf16(af1, bf, acc[t], 0, 0, 0);
      acc[t] = __builtin_amdgcn_mfma_f32_32x32x16_bf16(af3, bf, acc[t], 0, 0, 0);
    }
  }
  float bb[4];
#pragma unroll
  for (int t = 0; t < 4; ++t) bb[t] = nlb[nb * 128 + t * 32 + lm];
#pragma unroll
  for (int rr = 0; rr < 16; ++rr) {
    int r  = (rr & 3) + ((rr >> 2) << 3) + (hi << 2);
    int mo = mb * 128 + w * 32 + r;
    if (mo >= N_OUT) continue;
#pragma unroll
    for (int t = 0; t < 4; ++t)
      OutF[(size_t)mo * 256 + nb * 128 + t * 32 + lm] = tanh_fast(acc[t][rr] + bb[t]);
  }
}

// ---------------- final 4-way head ----------------
__global__ void pred_kernel(const float* __restrict__ outb,
                            const float* __restrict__ scW,
                            const float* __restrict__ scb,
                            float* __restrict__ pred) {
  int idx = blockIdx.x * blockDim.x + threadIdx.x;
  if (idx >= N_OUT * NDEC) return;
  int t = idx >> 2, e = idx & 3;
  const float* orow = outb + (size_t)t * HID;
  const float* wrow = scW + e * HID;
  float s = 0.f;
#pragma unroll 4
  for (int k = 0; k < HID; k += 4) {
    float4 ov = *(const float4*)(orow + k);
    float4 wv = *(const float4*)(wrow + k);
    s = fmaf(ov.x, wv.x, s);
    s = fmaf(ov.y, wv.y, s);
    s = fmaf(ov.z, wv.z, s);
    s = fmaf(ov.w, wv.w, s);
  }
  pred[idx] = s + scb[e];
}

extern "C" void kernel_launch(void* const* d_in, const int* in_sizes, int n_in,
                              void* d_out, int out_size, void* d_ws, size_t ws_size,
                              hipStream_t stream) {
  if (ws_size < WS_FLOATS * sizeof(float)) return;

  const float* train = (const float*)d_in[0];
  const int*   idxs  = (const int*)d_in[1];
  const float* a0    = (const float*)d_in[2];
  const float* tau_p = (const float*)d_in[3];
  const float* Wih[4] = {(const float*)d_in[4], (const float*)d_in[8],
                         (const float*)d_in[12], (const float*)d_in[16]};
  const float* Whh[4] = {(const float*)d_in[5], (const float*)d_in[9],
                         (const float*)d_in[13], (const float*)d_in[17]};
  const float* bih[4] = {(const float*)d_in[6], (const float*)d_in[10],
                         (const float*)d_in[14], (const float*)d_in[18]};
  const float* bhh[4] = {(const float*)d_in[7], (const float*)d_in[11],
                         (const float*)d_in[15], (const float*)d_in[19]};
  const float* nlW = (const float*)d_in[20];
  const float* nlb = (const float*)d_in[21];
  const float* scW = (const float*)d_in[22];
  const float* scb = (const float*)d_in[23];

  float* ws   = (float*)d_ws;
  float* levs = ws + LEVS_OFF;
  ushort_t* PBW[4]; ushort_t* PBI[4]; float* Bsum[4]; ushort_t* Hb[4];
  for (int lidx = 0; lidx < 4; ++lidx) {
    PBW[lidx]  = (ushort_t*)(ws + PBW_OFF(lidx));
    Bsum[lidx] = ws + BS_OFF(lidx);
    Hb[lidx]   = (ushort_t*)(ws + HB_OFF(lidx));
  }
  PBI[0] = (ushort_t*)(ws + PBI0_OFF);
  for (int lidx = 1; lidx < 4; ++lidx) PBI[lidx] = (ushort_t*)(ws + PBI_OFF(lidx));
  ushort_t* PBnl = (ushort_t*)(ws + PBNL_OFF);
  ushort_t* XPb  = (ushort_t*)(ws + XPB_OFF);
  float* OutF = ws + OUTF_OFF;

  // ---- packing ----
  for (int lidx = 0; lidx < 4; ++lidx)
    hipLaunchKernelGGL(pack_pb_kernel, dim3(1024), dim3(256), 0, stream, Whh[lidx], PBW[lidx], 16);
  hipLaunchKernelGGL(pack_pb_kernel, dim3(512), dim3(256), 0, stream, Wih[0], PBI[0], 8);
  for (int lidx = 1; lidx < 4; ++lidx)
    hipLaunchKernelGGL(pack_pb_kernel, dim3(1024), dim3(256), 0, stream, Wih[lidx], PBI[lidx], 16);
  for (int lidx = 0; lidx < 4; ++lidx)
    hipLaunchKernelGGL(pack_b_kernel, dim3(4), dim3(256), 0, stream, bih[lidx], bhh[lidx], Bsum[lidx]);
  hipLaunchKernelGGL(pack_nl_kernel, dim3(256), dim3(256), 0, stream, nlW, PBnl);

  // ---- levels + act ----
  hipLaunchKernelGGL(levels_kernel, dim3(128), dim3(256), 0, stream, train, idxs, a0, tau_p, levs);
  hipLaunchKernelGGL(act_kernel, dim3(510), dim3(256), 0, stream, train, levs,
                     (float*)d_out + (size_t)N_OUT * NDEC);

  // ---- layer 0: d=1, Sper=8149 ----
  hipLaunchKernelGGL(gemm_win_kernel, dim3(255, 4), dim3(256), 0, stream,
                     train, levs, PBI[0], Bsum[0], XPb);
  hipLaunchKernelGGL(lstm_mfma_kernel, dim3(255), dim3(256), 0, stream,
                     XPb, PBW[0], Hb[0], 1, 8149, 32593);
  // ---- layer 1: d=3, Sper=2717 ----
  hipLaunchKernelGGL(gemm_xp_kernel, dim3(255, 4), dim3(256), 0, stream,
                     Hb[0], PBI[1], Bsum[1], XPb);
  hipLaunchKernelGGL(lstm_mfma_kernel, dim3(255), dim3(256), 0, stream,
                     XPb, PBW[1], Hb[1], 3, 2717, 10865);
  // ---- layer 2: d=6, Sper=1359 ----
  hipLaunchKernelGGL(gemm_xp_kernel, dim3(255, 4), dim3(256), 0, stream,
                     Hb[1], PBI[2], Bsum[2], XPb);
  hipLaunchKernelGGL(lstm_mfma_kernel, dim3(255), dim3(256), 0, stream,
                     XPb, PBW[2], Hb[2], 6, 1359, 5433);
  // ---- layer 3: d=12, Sper=680 ----
  hipLaunchKernelGGL(gemm_xp_kernel, dim3(255, 4), dim3(256), 0, stream,
                     Hb[2], PBI[3], Bsum[3], XPb);
  hipLaunchKernelGGL(lstm_mfma_kernel, dim3(255), dim3(256), 0, stream,
                     XPb, PBW[3], Hb[3], 12, 680, 2717);

  // ---- epilogue ----
  hipLaunchKernelGGL(gemm_nl_kernel, dim3(255, 2), dim3(256), 0, stream,
                     Hb[1], Hb[3], PBnl, nlb, OutF);
  hipLaunchKernelGGL(pred_kernel, dim3(510), dim3(256), 0, stream,
                     OutF, scW, scb, (float*)d_out);
}